// Round 19
// baseline (91.688 us; speedup 1.0000x reference)
//
#include <hip/hip_runtime.h>
#include <math.h>

#define LEN 4096
#define LOG2LEN 12
#define DH 64
#define NBH 32      // B*H
#define KTOP 8
#define DPB 4       // d's per fwd block
#define NGRP (DH / DPB)                     // 16 partial slabs per bh

#define ZT_F2 ((size_t)NBH * DH * LEN)      // 8M float2 (67 MB)
#define PART_F2 ((size_t)NBH * NGRP * LEN)  // 2M float2 (16.8 MB)
#define SPEC_F2 (NBH * LEN)                 // 131072 float2 (1 MB)
#define TWO_PI 6.2831853071795864769f

// padded exchange layout: array a (=top digit), slot c in [0,256): a*272 + c
// (272 % 32 == 16 -> every exchange pattern is <=2-way conflicted = free)
#define XSTR 272

// base-16 digit reversal of a 12-bit index (3 hex digits)
__device__ __forceinline__ int rev16_12(int x) {
  return ((x & 15) << 8) | (x & 240) | (x >> 8);
}

// ---------------- in-register complex helpers / 16-point DFT ----------------
struct cf { float r, i; };
__device__ __forceinline__ cf cadd(const cf a, const cf b) { return {a.r + b.r, a.i + b.i}; }
__device__ __forceinline__ cf csub(const cf a, const cf b) { return {a.r - b.r, a.i - b.i}; }
__device__ __forceinline__ cf cmul(const cf a, const float wr, const float wi) {
  return {a.r * wr - a.i * wi, a.r * wi + a.i * wr};
}
// multiply by W^(N/4): forward (-i), inverse (+i)
template <int S>
__device__ __forceinline__ cf cmuli(const cf a) {
  return (S < 0) ? cf{a.i, -a.r} : cf{-a.i, a.r};
}
// multiply by (c, S*s)
template <int S>
__device__ __forceinline__ cf twc(const cf a, const float c, const float s) {
  return cmul(a, c, (S < 0) ? -s : s);
}
template <int S>
__device__ __forceinline__ void r4(cf& a, cf& b, cf& c, cf& d) {
  const cf t0 = cadd(a, c), t1 = csub(a, c), t2 = cadd(b, d), t3 = csub(b, d);
  const cf j3 = cmuli<S>(t3);
  a = cadd(t0, t2); c = csub(t0, t2);
  b = cadd(t1, j3); d = csub(t1, j3);
}
// 16-point DFT, natural order in and out, compile-time twiddles.
template <int S>
__device__ __forceinline__ void dft16(cf* x) {
  r4<S>(x[0], x[4], x[8], x[12]);
  r4<S>(x[1], x[5], x[9], x[13]);
  r4<S>(x[2], x[6], x[10], x[14]);
  r4<S>(x[3], x[7], x[11], x[15]);
  const float C1 = 0.92387953251128675613f;  // cos(pi/8)
  const float S1 = 0.38268343236508977173f;  // sin(pi/8)
  const float R2 = 0.70710678118654752440f;
  // slot n2+4k1 *= W16^{n2*k1}
  x[5] = twc<S>(x[5], C1, S1);
  x[6] = twc<S>(x[6], R2, R2);
  x[7] = twc<S>(x[7], S1, C1);
  x[9] = twc<S>(x[9], R2, R2);
  x[10] = cmuli<S>(x[10]);
  x[11] = twc<S>(x[11], -R2, R2);
  x[13] = twc<S>(x[13], S1, C1);
  x[14] = twc<S>(x[14], -R2, R2);
  x[15] = twc<S>(x[15], -C1, -S1);
  r4<S>(x[0], x[1], x[2], x[3]);
  r4<S>(x[4], x[5], x[6], x[7]);
  r4<S>(x[8], x[9], x[10], x[11]);
  r4<S>(x[12], x[13], x[14], x[15]);
  // slot(4k1+k2) holds X[4k2+k1] -> transpose to natural order
  cf t;
  t = x[1]; x[1] = x[4]; x[4] = t;
  t = x[2]; x[2] = x[8]; x[8] = t;
  t = x[3]; x[3] = x[12]; x[12] = t;
  t = x[6]; x[6] = x[9]; x[9] = t;
  t = x[7]; x[7] = x[13]; x[13] = t;
  t = x[11]; x[11] = x[14]; x[14] = t;
}

// ---------------------------------------------------------------------------
// Pass T: transpose q,k (bh,t,d) -> packed complex zT[(bh*64+d)*LEN + t],
// z = q + i*k. Coalesced both sides via padded LDS tiles. (proven rounds 2-8)
// ---------------------------------------------------------------------------
__global__ __launch_bounds__(256, 4) void ac_transpose(const float* __restrict__ q,
                                                       const float* __restrict__ k,
                                                       float2* __restrict__ zT) {
  __shared__ float tq[64][65], tk[64][65];
  const int bh = blockIdx.x >> 6;
  const int t0 = (blockIdx.x & 63) * 64;
  const int tid = threadIdx.x;
  const int tl = tid >> 2;
  const int c = tid & 3;
  const float* qb = q + ((size_t)bh * LEN + t0) * DH;
  const float* kb = k + ((size_t)bh * LEN + t0) * DH;
#pragma unroll
  for (int r = 0; r < 4; ++r) {
    const int d0 = (c + r * 4) * 4;
    const float4 vq = *reinterpret_cast<const float4*>(qb + (size_t)tl * DH + d0);
    const float4 vk = *reinterpret_cast<const float4*>(kb + (size_t)tl * DH + d0);
    tq[tl][d0] = vq.x; tq[tl][d0 + 1] = vq.y; tq[tl][d0 + 2] = vq.z; tq[tl][d0 + 3] = vq.w;
    tk[tl][d0] = vk.x; tk[tl][d0 + 1] = vk.y; tk[tl][d0 + 2] = vk.z; tk[tl][d0 + 3] = vk.w;
  }
  __syncthreads();
  const int d = tid >> 2;
  const int s = tid & 3;
  float2* ob = zT + ((size_t)(bh * DH + d)) * LEN + t0;
#pragma unroll
  for (int r = 0; r < 8; ++r) {
    const int t = (s + r * 4) * 2;
    const float4 o = make_float4(tq[t][d], tk[t][d], tq[t + 1][d], tk[t + 1][d]);
    *reinterpret_cast<float4*>(&ob[t]) = o;
  }
}

// ---------------------------------------------------------------------------
// Pass A: one block per (bh, d-quad). TR=true (normal): each d's slab is read
// COALESCED from zT (contiguous float2 -> no L2 line amplification, no
// 128-register hold); TR=false fallback: round-15 direct float4 loads with
// register hold. 4 serial FFTs (16x16x16: three in-register 16-pt DFTs + 2
// LDS exchanges), inline twiddles (stage-1 powers hoisted). Cross-spectrum
// P[f] = Q conj(K) = Im(A*B)/2 + i(|A|^2-|B|^2)/4 (A=Z[f], B=Z[-f])
// accumulated in LDS; one partial slab per block (16 per bh). Wave-barrier
// elision for the intra-wave stage2->stage3 exchange (round-15 proven).
// ---------------------------------------------------------------------------
template <bool TR>
__global__ __launch_bounds__(256, 2) void ac_fft_fwd(const float* __restrict__ q,
                                                     const float* __restrict__ k,
                                                     const float2* __restrict__ zT,
                                                     float2* __restrict__ part) {
  __shared__ float lre[16 * XSTR], lim[16 * XSTR];  // 34.8 KB
  __shared__ float2 acc[LEN];                       // 32 KB accumulator
  const int tid = threadIdx.x;
  const int hi = tid >> 4, lo = tid & 15;
  // bijective 512-block swizzle: XCD x owns bh [4x, 4x+4)
  const int bid = (int)blockIdx.x;
  const int task = ((bid & 7) << 6) | (bid >> 3);
  const int bh = task >> 4;
  const int g = task & 15;

  // twiddle bases (per-thread constants)
  float s1, c1, s2, c2;
  sincosf(-TWO_PI * (float)tid / (float)LEN, &s1, &c1);        // w1 = W4096^tid
  sincosf(-TWO_PI * (float)lo / 256.0f, &s2, &c2);             // w2 = W256^lo
  // hoist stage-1 twiddle powers w1^k, k=1..15 (d-invariant)
  float w1pr[15], w1pi[15];
  {
    float cr = c1, ci = s1;
#pragma unroll
    for (int kk = 0; kk < 15; ++kk) {
      w1pr[kk] = cr; w1pi[kk] = ci;
      const float nr = cr * c1 - ci * s1;
      ci = cr * s1 + ci * c1;
      cr = nr;
    }
  }

#pragma unroll
  for (int i = 0; i < 16; ++i) acc[tid + 256 * i] = make_float2(0.f, 0.f);

  // fallback path only: hold 4 d-columns in registers
  float hq[TR ? 1 : DPB][16], hk[TR ? 1 : DPB][16];
  if (!TR) {
    const float* qb = q + (size_t)bh * LEN * DH + 4 * g;
    const float* kb = k + (size_t)bh * LEN * DH + 4 * g;
#pragma unroll
    for (int n1 = 0; n1 < 16; ++n1) {
      const size_t off = (size_t)(tid + 256 * n1) * DH;
      const float4 q4 = *reinterpret_cast<const float4*>(qb + off);
      const float4 k4 = *reinterpret_cast<const float4*>(kb + off);
      hq[0][n1] = q4.x; hq[1 % (TR ? 1 : DPB)][n1] = q4.y;
      hq[2 % (TR ? 1 : DPB)][n1] = q4.z; hq[3 % (TR ? 1 : DPB)][n1] = q4.w;
      hk[0][n1] = k4.x; hk[1 % (TR ? 1 : DPB)][n1] = k4.y;
      hk[2 % (TR ? 1 : DPB)][n1] = k4.z; hk[3 % (TR ? 1 : DPB)][n1] = k4.w;
    }
  }

#pragma unroll 1
  for (int dd = 0; dd < DPB; ++dd) {
    cf x[16];
    if (TR) {
      // coalesced float2 slab read: wave = 512B contiguous per instruction
      const float2* zb = zT + (size_t)(bh * DH + g * DPB + dd) * LEN;
#pragma unroll
      for (int n1 = 0; n1 < 16; ++n1) {
        const float2 z = zb[tid + 256 * n1];
        x[n1].r = z.x; x[n1].i = z.y;
      }
    } else {
#pragma unroll
      for (int n1 = 0; n1 < 16; ++n1) {
        x[n1].r = hq[dd % (TR ? 1 : DPB)][n1];
        x[n1].i = hk[dd % (TR ? 1 : DPB)][n1];
      }
    }
    // stage 1: DFT over n1 (stride 256), twiddle W4096^{tid*k1} = w1p[k1-1]
    dft16<-1>(x);
#pragma unroll
    for (int k1 = 1; k1 < 16; ++k1) x[k1] = cmul(x[k1], w1pr[k1 - 1], w1pi[k1 - 1]);
    __syncthreads();  // A: previous iteration's pairing reads done (cross-wave WAR)
#pragma unroll
    for (int k1 = 0; k1 < 16; ++k1) {
      lre[k1 * XSTR + tid] = x[k1].r;
      lim[k1 * XSTR + tid] = x[k1].i;
    }
    __syncthreads();  // B: stage-2 reads row hi written by all columns (cross-wave RAW)
    // stage 2 inputs: fixed (k1=hi, m2=lo), over m1
#pragma unroll
    for (int m1 = 0; m1 < 16; ++m1) {
      const int a = hi * XSTR + 16 * m1 + lo;
      x[m1].r = lre[a]; x[m1].i = lim[a];
    }
    dft16<-1>(x);
    {  // twiddle W256^{lo*j1} = w2^j1
      float cr = c2, ci = s2;
#pragma unroll
      for (int j1 = 1; j1 < 16; ++j1) {
        x[j1] = cmul(x[j1], cr, ci);
        const float nr = cr * c2 - ci * s2;
        ci = cr * s2 + ci * c2;
        cr = nr;
      }
    }
    // stage2->stage3 exchange confined to row hi = own 16-lane group (one
    // wave64): per-wave LDS in-order guarantees RAW/WAR; fence compiler only.
    __builtin_amdgcn_wave_barrier();
#pragma unroll
    for (int j1 = 0; j1 < 16; ++j1) {
      lre[hi * XSTR + 16 * j1 + lo] = x[j1].r;
      lim[hi * XSTR + 16 * j1 + lo] = x[j1].i;
    }
    __builtin_amdgcn_wave_barrier();
    // stage 3 inputs: fixed (k1=hi, j1=lo), over m2 (contiguous 16)
#pragma unroll
    for (int m2 = 0; m2 < 16; ++m2) {
      const int a = hi * XSTR + 16 * lo + m2;
      x[m2].r = lre[a]; x[m2].i = lim[a];
    }
    dft16<-1>(x);
    __builtin_amdgcn_wave_barrier();  // stage-3 write overwrites own-group rows only
#pragma unroll
    for (int j2 = 0; j2 < 16; ++j2) {  // p = 256*hi + 16*lo + j2
      lre[hi * XSTR + 16 * lo + j2] = x[j2].r;
      lim[hi * XSTR + 16 * lo + j2] = x[j2].i;
    }
    __syncthreads();  // F: pairing reads arbitrary rows (cross-wave RAW)
    // cross-spectrum pairing (position p holds Z[rev16(p)]); accumulate in
    // LDS (each p owned by exactly one thread -> race-free rmw)
#pragma unroll
    for (int i = 0; i < 16; ++i) {
      const int p = tid + 256 * i;
      const int f = rev16_12(p);
      const int f2 = (LEN - f) & (LEN - 1);
      const int p2 = rev16_12(f2);
      const int a1 = i * XSTR + tid;
      const int a2 = (p2 >> 8) * XSTR + (p2 & 255);
      const float ar = lre[a1], ai = lim[a1];
      const float br = lre[a2], bi = lim[a2];
      float2 a = acc[p];
      a.x += 0.5f * (ar * bi + ai * br);
      a.y += 0.25f * ((ar * ar + ai * ai) - (br * br + bi * bi));
      acc[p] = a;
    }
  }
  // write the block's partial slab (coalesced float2); acc[p] was written by
  // this same thread -> no barrier needed
  float2* op = part + (size_t)(bh * NGRP + g) * LEN;
#pragma unroll
  for (int i = 0; i < 16; ++i) {
    const int p = tid + 256 * i;
    op[p] = acc[p];
  }
}

// ---------------------------------------------------------------------------
// Pass R: sum 16 partial spectra -> spec[bh][p]. Grid NBH*16 (512 blocks),
// coalesced, BW-bound.
// ---------------------------------------------------------------------------
__global__ __launch_bounds__(256) void ac_reduce(const float2* __restrict__ part,
                                                 float2* __restrict__ spec) {
  const int bh = blockIdx.x >> 4;
  const int p = ((blockIdx.x & 15) << 8) | threadIdx.x;
  float accr = 0.f, acci = 0.f;
#pragma unroll 4
  for (int g = 0; g < NGRP; ++g) {
    const float2 v = part[((size_t)(bh * NGRP + g) << LOG2LEN) + p];
    accr += v.x; acci += v.y;
  }
  spec[((size_t)bh << LOG2LEN) + p] = make_float2(accr, acci);
}

// ---------------------------------------------------------------------------
// Pass B+C: per (b,h): inverse FFT 16x16x16 (digit-reversed in -> natural
// out) reading the 1 MB spec (L2-hot), inline twiddles, fused top-8 +
// softmax. Stage A->B exchange is own-16-lane-group -> wave_barrier only.
// ---------------------------------------------------------------------------
__global__ __launch_bounds__(256, 2) void ac_fft_inv(const float2* __restrict__ spec,
                                                     float* __restrict__ attn,
                                                     int* __restrict__ delays) {
  __shared__ float lre[16 * XSTR], lim[16 * XSTR];
  __shared__ float rv[256];
  __shared__ int ri[256];
  __shared__ float selv[KTOP];
  __shared__ int seli[KTOP];
  const int bh = blockIdx.x;
  const int tid = threadIdx.x;
  const int hi = tid >> 4, lo = tid & 15;

  // input: position p = 16*tid + f2 holds P[rev16(p)]; thread = (f0=hi, f1=lo)
  cf x[16];
  {
    const float4* b4 = reinterpret_cast<const float4*>(spec + ((size_t)bh << LOG2LEN) + 16 * tid);
#pragma unroll
    for (int i = 0; i < 8; ++i) {
      const float4 vv = b4[i];
      x[2 * i].r = vv.x; x[2 * i].i = vv.y;
      x[2 * i + 1].r = vv.z; x[2 * i + 1].i = vv.w;
    }
  }

  // twiddle bases
  float sA, cA, sB0, cB0, sBs, cBs;
  sincosf(TWO_PI * (float)lo / 256.0f, &sA, &cA);                       // W4096^{16 lo}
  sincosf(TWO_PI * (float)(hi * lo) / (float)LEN, &sB0, &cB0);          // W4096^{hi*lo}
  sincosf(TWO_PI * (float)hi / 256.0f, &sBs, &cBs);                     // W4096^{16 hi}

  // stage A: DFT over f2 -> A1[t0]; twiddle W4096^{16*lo*t0} = wA^t0
  dft16<1>(x);
  {
    float cr = cA, ci = sA;
#pragma unroll
    for (int t0 = 1; t0 < 16; ++t0) {
      x[t0] = cmul(x[t0], cr, ci);
      const float nr = cr * cA - ci * sA;
      ci = cr * sA + ci * cA;
      cr = nr;
    }
  }
#pragma unroll
  for (int t0 = 0; t0 < 16; ++t0) {
    lre[hi * XSTR + 16 * t0 + lo] = x[t0].r;
    lim[hi * XSTR + 16 * t0 + lo] = x[t0].i;
  }
  // stage A write and stage B read both confined to row hi = own wave group
  __builtin_amdgcn_wave_barrier();
  // stage B: thread (f0=hi, t0=lo), over f1 (contiguous)
#pragma unroll
  for (int f1 = 0; f1 < 16; ++f1) {
    const int a = hi * XSTR + 16 * lo + f1;
    x[f1].r = lre[a]; x[f1].i = lim[a];
  }
  dft16<1>(x);
  {  // twiddle W4096^{hi*(16*t1+lo)} = wB0 * wBs^t1
    float cr = cB0, ci = sB0;
#pragma unroll
    for (int t1 = 0; t1 < 16; ++t1) {
      x[t1] = cmul(x[t1], cr, ci);
      const float nr = cr * cBs - ci * sBs;
      ci = cr * sBs + ci * cBs;
      cr = nr;
    }
  }
  __builtin_amdgcn_wave_barrier();  // stage-B write overwrites own-group rows
#pragma unroll
  for (int t1 = 0; t1 < 16; ++t1) {
    lre[hi * XSTR + 16 * t1 + lo] = x[t1].r;
    lim[hi * XSTR + 16 * t1 + lo] = x[t1].i;
  }
  __syncthreads();  // stage-C reads all rows (cross-wave RAW)
  // stage C: thread (t1=hi, t0=lo), over f0 (stride XSTR)
#pragma unroll
  for (int f0 = 0; f0 < 16; ++f0) {
    const int a = f0 * XSTR + 16 * hi + lo;
    x[f0].r = lre[a]; x[f0].i = lim[a];
  }
  dft16<1>(x);
  __syncthreads();  // stage-C reads done; reuse lre as vals[4096]
  const float scale = 1.0f / ((float)LEN * (float)DH);
#pragma unroll
  for (int t2 = 0; t2 < 16; ++t2) lre[256 * t2 + tid] = x[t2].r * scale;  // t = 256*t2 + tid
  __syncthreads();

  // top-8 + softmax on vals = lre[0..4095]
  for (int kk = 0; kk < KTOP; ++kk) {
    float mv = -3.0e38f;
    int mi = 0;
    for (int t = tid; t < LEN; t += 256) {
      const float xv = lre[t];
      if (xv > mv) { mv = xv; mi = t; }
    }
    rv[tid] = mv; ri[tid] = mi;
    __syncthreads();
    for (int s = 128; s > 0; s >>= 1) {
      if (tid < s) {
        if (rv[tid + s] > rv[tid]) { rv[tid] = rv[tid + s]; ri[tid] = ri[tid + s]; }
      }
      __syncthreads();
    }
    if (tid == 0) {
      selv[kk] = rv[0];
      seli[kk] = ri[0];
      lre[ri[0]] = -3.0e38f;
    }
    __syncthreads();
  }
  if (tid == 0) {
    const float mx = selv[0];
    float ex[KTOP];
    float sum = 0.f;
    for (int j = 0; j < KTOP; ++j) { ex[j] = expf(selv[j] - mx); sum += ex[j]; }
    const float inv = 1.0f / sum;
    for (int j = 0; j < KTOP; ++j) {
      attn[bh * KTOP + j] = ex[j] * inv;
      delays[bh * KTOP + j] = seli[j];
    }
  }
}

// ---------------------------------------------------------------------------
// Pass D: out[bh,t,d] = sum_j attn_j * v[bh,(t-delay_j) mod L, d], float4.
// ---------------------------------------------------------------------------
__global__ __launch_bounds__(256) void ac_gather(const float* __restrict__ v,
                                                 const float* __restrict__ attn,
                                                 const int* __restrict__ delays,
                                                 float* __restrict__ out) {
  const int bx = blockIdx.x;
  const int xcd = bx & 7;
  const int i = bx >> 3;
  const int bh = (xcd << 2) | (i & 3);
  const int chunk = i >> 2;
  const int tid = threadIdx.x;
  float aw[KTOP];
  int dl[KTOP];
#pragma unroll
  for (int j = 0; j < KTOP; ++j) {
    aw[j] = attn[bh * KTOP + j];
    dl[j] = delays[bh * KTOP + j];
  }
  const int e = chunk * 1024 + tid * 4;
  const int t = e >> 6;
  const int d = e & 63;
  const float* vb = v + (size_t)bh * LEN * DH;
  float4 acc = make_float4(0.f, 0.f, 0.f, 0.f);
#pragma unroll
  for (int j = 0; j < KTOP; ++j) {
    int src = t - dl[j];
    if (src < 0) src += LEN;
    const float4 vv = *reinterpret_cast<const float4*>(vb + (size_t)src * DH + d);
    acc.x += aw[j] * vv.x;
    acc.y += aw[j] * vv.y;
    acc.z += aw[j] * vv.z;
    acc.w += aw[j] * vv.w;
  }
  *reinterpret_cast<float4*>(out + (size_t)bh * LEN * DH + e) = acc;
}

extern "C" void kernel_launch(void* const* d_in, const int* in_sizes, int n_in,
                              void* d_out, int out_size, void* d_ws, size_t ws_size,
                              hipStream_t stream) {
  const float* q = (const float*)d_in[0];
  const float* k = (const float*)d_in[1];
  const float* v = (const float*)d_in[2];
  float* out = (float*)d_out;

  // ws layout (TR): zT (67 MB) | part (16.8 MB) | spec (1 MB) | attn | delays
  const size_t need = ZT_F2 * 8 + PART_F2 * 8 + (size_t)SPEC_F2 * 8 +
                      (size_t)NBH * KTOP * 8;
  const bool tr = (ws_size >= need);

  float2* zT = (float2*)d_ws;
  float2* part = tr ? (zT + ZT_F2) : zT;  // no-TR: zT unused, part at base
  float2* spec = part + PART_F2;
  float* attn = (float*)(spec + SPEC_F2);
  int* delays = (int*)(attn + NBH * KTOP);

  if (tr) {
    ac_transpose<<<dim3(NBH * 64), dim3(256), 0, stream>>>(q, k, zT);
    ac_fft_fwd<true><<<dim3(NBH * NGRP), dim3(256), 0, stream>>>(q, k, zT, part);
  } else {
    ac_fft_fwd<false><<<dim3(NBH * NGRP), dim3(256), 0, stream>>>(q, k, zT, part);
  }
  ac_reduce<<<dim3(NBH * NGRP), dim3(256), 0, stream>>>(part, spec);
  ac_fft_inv<<<dim3(NBH), dim3(256), 0, stream>>>(spec, attn, delays);
  ac_gather<<<dim3(NBH * 256), dim3(256), 0, stream>>>(v, attn, delays, out);
}

// Round 20
// 82.597 us; speedup vs baseline: 1.1101x; 1.1101x over previous
//
#include <hip/hip_runtime.h>
#include <math.h>

#define LEN 4096
#define LOG2LEN 12
#define DH 64
#define NBH 32      // B*H
#define KTOP 8
#define DPB 4       // d's per fwd block (register-held)
#define NGRP (DH / DPB)                     // 16 partial slabs per bh

#define PART_F2 ((size_t)NBH * NGRP * LEN)  // 2M float2 (16.8 MB)
#define SPEC_F2 (NBH * LEN)                 // 131072 float2 (1 MB)
#define TWO_PI 6.2831853071795864769f

// padded exchange layout: array a (=top digit), slot c in [0,256): a*272 + c
// (272 % 32 == 16 -> every exchange pattern is <=2-way conflicted = free)
#define XSTR 272

// base-16 digit reversal of a 12-bit index (3 hex digits)
__device__ __forceinline__ int rev16_12(int x) {
  return ((x & 15) << 8) | (x & 240) | (x >> 8);
}

// ---------------- in-register complex helpers / 16-point DFT ----------------
struct cf { float r, i; };
__device__ __forceinline__ cf cadd(const cf a, const cf b) { return {a.r + b.r, a.i + b.i}; }
__device__ __forceinline__ cf csub(const cf a, const cf b) { return {a.r - b.r, a.i - b.i}; }
__device__ __forceinline__ cf cmul(const cf a, const float wr, const float wi) {
  return {a.r * wr - a.i * wi, a.r * wi + a.i * wr};
}
// multiply by W^(N/4): forward (-i), inverse (+i)
template <int S>
__device__ __forceinline__ cf cmuli(const cf a) {
  return (S < 0) ? cf{a.i, -a.r} : cf{-a.i, a.r};
}
// multiply by (c, S*s)
template <int S>
__device__ __forceinline__ cf twc(const cf a, const float c, const float s) {
  return cmul(a, c, (S < 0) ? -s : s);
}
template <int S>
__device__ __forceinline__ void r4(cf& a, cf& b, cf& c, cf& d) {
  const cf t0 = cadd(a, c), t1 = csub(a, c), t2 = cadd(b, d), t3 = csub(b, d);
  const cf j3 = cmuli<S>(t3);
  a = cadd(t0, t2); c = csub(t0, t2);
  b = cadd(t1, j3); d = csub(t1, j3);
}
// 16-point DFT, natural order in and out, compile-time twiddles.
template <int S>
__device__ __forceinline__ void dft16(cf* x) {
  r4<S>(x[0], x[4], x[8], x[12]);
  r4<S>(x[1], x[5], x[9], x[13]);
  r4<S>(x[2], x[6], x[10], x[14]);
  r4<S>(x[3], x[7], x[11], x[15]);
  const float C1 = 0.92387953251128675613f;  // cos(pi/8)
  const float S1 = 0.38268343236508977173f;  // sin(pi/8)
  const float R2 = 0.70710678118654752440f;
  // slot n2+4k1 *= W16^{n2*k1}
  x[5] = twc<S>(x[5], C1, S1);
  x[6] = twc<S>(x[6], R2, R2);
  x[7] = twc<S>(x[7], S1, C1);
  x[9] = twc<S>(x[9], R2, R2);
  x[10] = cmuli<S>(x[10]);
  x[11] = twc<S>(x[11], -R2, R2);
  x[13] = twc<S>(x[13], S1, C1);
  x[14] = twc<S>(x[14], -R2, R2);
  x[15] = twc<S>(x[15], -C1, -S1);
  r4<S>(x[0], x[1], x[2], x[3]);
  r4<S>(x[4], x[5], x[6], x[7]);
  r4<S>(x[8], x[9], x[10], x[11]);
  r4<S>(x[12], x[13], x[14], x[15]);
  // slot(4k1+k2) holds X[4k2+k1] -> transpose to natural order
  cf t;
  t = x[1]; x[1] = x[4]; x[4] = t;
  t = x[2]; x[2] = x[8]; x[8] = t;
  t = x[3]; x[3] = x[12]; x[12] = t;
  t = x[6]; x[6] = x[9]; x[9] = t;
  t = x[7]; x[7] = x[13]; x[13] = t;
  t = x[11]; x[11] = x[14]; x[14] = t;
}

// ---------------------------------------------------------------------------
// Pass A: one block per (bh, d-quad). One float4-per-row pass over the bh
// slab: thread holds all four d-columns for its 16 rows in registers
// (hq/hk[4][16], statically indexed). Then 4 serial FFTs (16x16x16: three
// in-register 16-pt DFTs + 2 LDS exchanges), inline twiddles (stage-1 powers
// w1p[] hoisted out of the d loop). Cross-spectrum P[f] = Q conj(K) =
// Im(A*B)/2 + i(|A|^2-|B|^2)/4 (A=Z[f], B=Z[-f]) accumulated in an LDS
// buffer; one partial slab per block (16 per bh).
// BARRIER ELISION: the stage2->stage3 exchange moves data only within a
// 16-lane hi-group (all addresses row = tid>>4) -> same wave64. Per-wave LDS
// ops complete in order, so those 3 __syncthreads per d are replaced by free
// __builtin_amdgcn_wave_barrier() compiler fences: 6 -> 3 barriers per d.
// ---------------------------------------------------------------------------
__global__ __launch_bounds__(256, 2) void ac_fft_fwd(const float* __restrict__ q,
                                                     const float* __restrict__ k,
                                                     float2* __restrict__ part) {
  __shared__ float lre[16 * XSTR], lim[16 * XSTR];  // 34.8 KB
  __shared__ float2 acc[LEN];                       // 32 KB accumulator
  const int tid = threadIdx.x;
  const int hi = tid >> 4, lo = tid & 15;
  // bijective 512-block swizzle: XCD x owns bh [4x, 4x+4)
  const int bid = (int)blockIdx.x;
  const int task = ((bid & 7) << 6) | (bid >> 3);
  const int bh = task >> 4;
  const int g = task & 15;

  // twiddle bases (per-thread constants)
  float s1, c1, s2, c2;
  sincosf(-TWO_PI * (float)tid / (float)LEN, &s1, &c1);        // w1 = W4096^tid
  sincosf(-TWO_PI * (float)lo / 256.0f, &s2, &c2);             // w2 = W256^lo
  // hoist stage-1 twiddle powers w1^k, k=1..15 (d-invariant; kills the
  // 15-long serial cmul chain from each d iteration)
  float w1pr[15], w1pi[15];
  {
    float cr = c1, ci = s1;
#pragma unroll
    for (int kk = 0; kk < 15; ++kk) {
      w1pr[kk] = cr; w1pi[kk] = ci;
      const float nr = cr * c1 - ci * s1;
      ci = cr * s1 + ci * c1;
      cr = nr;
    }
  }

#pragma unroll
  for (int i = 0; i < 16; ++i) acc[tid + 256 * i] = make_float2(0.f, 0.f);

  // load & hold: 4 d-columns, 16 rows each (all indices compile-time)
  float hq[DPB][16], hk[DPB][16];
  {
    const float* qb = q + (size_t)bh * LEN * DH + 4 * g;
    const float* kb = k + (size_t)bh * LEN * DH + 4 * g;
#pragma unroll
    for (int n1 = 0; n1 < 16; ++n1) {
      const size_t off = (size_t)(tid + 256 * n1) * DH;
      const float4 q4 = *reinterpret_cast<const float4*>(qb + off);
      const float4 k4 = *reinterpret_cast<const float4*>(kb + off);
      hq[0][n1] = q4.x; hq[1][n1] = q4.y; hq[2][n1] = q4.z; hq[3][n1] = q4.w;
      hk[0][n1] = k4.x; hk[1][n1] = k4.y; hk[2][n1] = k4.z; hk[3][n1] = k4.w;
    }
  }

#pragma unroll
  for (int dd = 0; dd < DPB; ++dd) {
    cf x[16];
#pragma unroll
    for (int n1 = 0; n1 < 16; ++n1) { x[n1].r = hq[dd][n1]; x[n1].i = hk[dd][n1]; }
    // stage 1: DFT over n1 (stride 256), twiddle W4096^{tid*k1} = w1p[k1-1]
    dft16<-1>(x);
#pragma unroll
    for (int k1 = 1; k1 < 16; ++k1) x[k1] = cmul(x[k1], w1pr[k1 - 1], w1pi[k1 - 1]);
    __syncthreads();  // A: previous iteration's pairing reads complete (cross-wave WAR)
#pragma unroll
    for (int k1 = 0; k1 < 16; ++k1) {
      lre[k1 * XSTR + tid] = x[k1].r;
      lim[k1 * XSTR + tid] = x[k1].i;
    }
    __syncthreads();  // B: stage-2 reads row hi written by all columns (cross-wave RAW)
    // stage 2 inputs: fixed (k1=hi, m2=lo), over m1
#pragma unroll
    for (int m1 = 0; m1 < 16; ++m1) {
      const int a = hi * XSTR + 16 * m1 + lo;
      x[m1].r = lre[a]; x[m1].i = lim[a];
    }
    dft16<-1>(x);
    {  // twiddle W256^{lo*j1} = w2^j1
      float cr = c2, ci = s2;
#pragma unroll
      for (int j1 = 1; j1 < 16; ++j1) {
        x[j1] = cmul(x[j1], cr, ci);
        const float nr = cr * c2 - ci * s2;
        ci = cr * s2 + ci * c2;
        cr = nr;
      }
    }
    // stage2->stage3 exchange is confined to row hi = own 16-lane group (one
    // wave64): per-wave LDS in-order guarantees RAW/WAR; fence compiler only.
    __builtin_amdgcn_wave_barrier();
#pragma unroll
    for (int j1 = 0; j1 < 16; ++j1) {
      lre[hi * XSTR + 16 * j1 + lo] = x[j1].r;
      lim[hi * XSTR + 16 * j1 + lo] = x[j1].i;
    }
    __builtin_amdgcn_wave_barrier();
    // stage 3 inputs: fixed (k1=hi, j1=lo), over m2 (contiguous 16)
#pragma unroll
    for (int m2 = 0; m2 < 16; ++m2) {
      const int a = hi * XSTR + 16 * lo + m2;
      x[m2].r = lre[a]; x[m2].i = lim[a];
    }
    dft16<-1>(x);
    __builtin_amdgcn_wave_barrier();  // stage-3 write overwrites own-group rows only
#pragma unroll
    for (int j2 = 0; j2 < 16; ++j2) {  // p = 256*hi + 16*lo + j2
      lre[hi * XSTR + 16 * lo + j2] = x[j2].r;
      lim[hi * XSTR + 16 * lo + j2] = x[j2].i;
    }
    __syncthreads();  // F: pairing reads arbitrary rows (cross-wave RAW)
    // cross-spectrum pairing (position p holds Z[rev16(p)]); accumulate in
    // LDS (each p owned by exactly one thread -> race-free rmw)
#pragma unroll
    for (int i = 0; i < 16; ++i) {
      const int p = tid + 256 * i;
      const int f = rev16_12(p);
      const int f2 = (LEN - f) & (LEN - 1);
      const int p2 = rev16_12(f2);
      const int a1 = i * XSTR + tid;
      const int a2 = (p2 >> 8) * XSTR + (p2 & 255);
      const float ar = lre[a1], ai = lim[a1];
      const float br = lre[a2], bi = lim[a2];
      float2 a = acc[p];
      a.x += 0.5f * (ar * bi + ai * br);
      a.y += 0.25f * ((ar * ar + ai * ai) - (br * br + bi * bi));
      acc[p] = a;
    }
  }
  // write the block's partial slab (coalesced float2); acc[p] was written by
  // this same thread -> no barrier needed
  float2* op = part + (size_t)(bh * NGRP + g) * LEN;
#pragma unroll
  for (int i = 0; i < 16; ++i) {
    const int p = tid + 256 * i;
    op[p] = acc[p];
  }
}

// ---------------------------------------------------------------------------
// Pass R: sum 16 partial spectra -> spec[bh][p]. Grid NBH*16 (512 blocks),
// coalesced, BW-bound.
// ---------------------------------------------------------------------------
__global__ __launch_bounds__(256) void ac_reduce(const float2* __restrict__ part,
                                                 float2* __restrict__ spec) {
  const int bh = blockIdx.x >> 4;
  const int p = ((blockIdx.x & 15) << 8) | threadIdx.x;
  float accr = 0.f, acci = 0.f;
#pragma unroll 4
  for (int g = 0; g < NGRP; ++g) {
    const float2 v = part[((size_t)(bh * NGRP + g) << LOG2LEN) + p];
    accr += v.x; acci += v.y;
  }
  spec[((size_t)bh << LOG2LEN) + p] = make_float2(accr, acci);
}

// ---------------------------------------------------------------------------
// Pass B+C: per (b,h): inverse FFT 16x16x16 (digit-reversed in -> natural
// out) reading the 1 MB spec (L2-hot), inline twiddles, fused top-8 +
// softmax. Stage A->B exchange is own-16-lane-group -> wave_barrier only.
// ---------------------------------------------------------------------------
__global__ __launch_bounds__(256, 2) void ac_fft_inv(const float2* __restrict__ spec,
                                                     float* __restrict__ attn,
                                                     int* __restrict__ delays) {
  __shared__ float lre[16 * XSTR], lim[16 * XSTR];
  __shared__ float rv[256];
  __shared__ int ri[256];
  __shared__ float selv[KTOP];
  __shared__ int seli[KTOP];
  const int bh = blockIdx.x;
  const int tid = threadIdx.x;
  const int hi = tid >> 4, lo = tid & 15;

  // input: position p = 16*tid + f2 holds P[rev16(p)]; thread = (f0=hi, f1=lo)
  cf x[16];
  {
    const float4* b4 = reinterpret_cast<const float4*>(spec + ((size_t)bh << LOG2LEN) + 16 * tid);
#pragma unroll
    for (int i = 0; i < 8; ++i) {
      const float4 vv = b4[i];
      x[2 * i].r = vv.x; x[2 * i].i = vv.y;
      x[2 * i + 1].r = vv.z; x[2 * i + 1].i = vv.w;
    }
  }

  // twiddle bases
  float sA, cA, sB0, cB0, sBs, cBs;
  sincosf(TWO_PI * (float)lo / 256.0f, &sA, &cA);                       // W4096^{16 lo}
  sincosf(TWO_PI * (float)(hi * lo) / (float)LEN, &sB0, &cB0);          // W4096^{hi*lo}
  sincosf(TWO_PI * (float)hi / 256.0f, &sBs, &cBs);                     // W4096^{16 hi}

  // stage A: DFT over f2 -> A1[t0]; twiddle W4096^{16*lo*t0} = wA^t0
  dft16<1>(x);
  {
    float cr = cA, ci = sA;
#pragma unroll
    for (int t0 = 1; t0 < 16; ++t0) {
      x[t0] = cmul(x[t0], cr, ci);
      const float nr = cr * cA - ci * sA;
      ci = cr * sA + ci * cA;
      cr = nr;
    }
  }
#pragma unroll
  for (int t0 = 0; t0 < 16; ++t0) {
    lre[hi * XSTR + 16 * t0 + lo] = x[t0].r;
    lim[hi * XSTR + 16 * t0 + lo] = x[t0].i;
  }
  // stage A write and stage B read both confined to row hi = own wave group
  __builtin_amdgcn_wave_barrier();
  // stage B: thread (f0=hi, t0=lo), over f1 (contiguous)
#pragma unroll
  for (int f1 = 0; f1 < 16; ++f1) {
    const int a = hi * XSTR + 16 * lo + f1;
    x[f1].r = lre[a]; x[f1].i = lim[a];
  }
  dft16<1>(x);
  {  // twiddle W4096^{hi*(16*t1+lo)} = wB0 * wBs^t1
    float cr = cB0, ci = sB0;
#pragma unroll
    for (int t1 = 0; t1 < 16; ++t1) {
      x[t1] = cmul(x[t1], cr, ci);
      const float nr = cr * cBs - ci * sBs;
      ci = cr * sBs + ci * cBs;
      cr = nr;
    }
  }
  __builtin_amdgcn_wave_barrier();  // stage-B write overwrites own-group rows
#pragma unroll
  for (int t1 = 0; t1 < 16; ++t1) {
    lre[hi * XSTR + 16 * t1 + lo] = x[t1].r;
    lim[hi * XSTR + 16 * t1 + lo] = x[t1].i;
  }
  __syncthreads();  // stage-C reads all rows (cross-wave RAW)
  // stage C: thread (t1=hi, t0=lo), over f0 (stride XSTR)
#pragma unroll
  for (int f0 = 0; f0 < 16; ++f0) {
    const int a = f0 * XSTR + 16 * hi + lo;
    x[f0].r = lre[a]; x[f0].i = lim[a];
  }
  dft16<1>(x);
  __syncthreads();  // stage-C reads done; reuse lre as vals[4096]
  const float scale = 1.0f / ((float)LEN * (float)DH);
#pragma unroll
  for (int t2 = 0; t2 < 16; ++t2) lre[256 * t2 + tid] = x[t2].r * scale;  // t = 256*t2 + tid
  __syncthreads();

  // top-8 + softmax on vals = lre[0..4095]
  for (int kk = 0; kk < KTOP; ++kk) {
    float mv = -3.0e38f;
    int mi = 0;
    for (int t = tid; t < LEN; t += 256) {
      const float xv = lre[t];
      if (xv > mv) { mv = xv; mi = t; }
    }
    rv[tid] = mv; ri[tid] = mi;
    __syncthreads();
    for (int s = 128; s > 0; s >>= 1) {
      if (tid < s) {
        if (rv[tid + s] > rv[tid]) { rv[tid] = rv[tid + s]; ri[tid] = ri[tid + s]; }
      }
      __syncthreads();
    }
    if (tid == 0) {
      selv[kk] = rv[0];
      seli[kk] = ri[0];
      lre[ri[0]] = -3.0e38f;
    }
    __syncthreads();
  }
  if (tid == 0) {
    const float mx = selv[0];
    float ex[KTOP];
    float sum = 0.f;
    for (int j = 0; j < KTOP; ++j) { ex[j] = expf(selv[j] - mx); sum += ex[j]; }
    const float inv = 1.0f / sum;
    for (int j = 0; j < KTOP; ++j) {
      attn[bh * KTOP + j] = ex[j] * inv;
      delays[bh * KTOP + j] = seli[j];
    }
  }
}

// ---------------------------------------------------------------------------
// Pass D: out[bh,t,d] = sum_j attn_j * v[bh,(t-delay_j) mod L, d], float4.
// ---------------------------------------------------------------------------
__global__ __launch_bounds__(256) void ac_gather(const float* __restrict__ v,
                                                 const float* __restrict__ attn,
                                                 const int* __restrict__ delays,
                                                 float* __restrict__ out) {
  const int bx = blockIdx.x;
  const int xcd = bx & 7;
  const int i = bx >> 3;
  const int bh = (xcd << 2) | (i & 3);
  const int chunk = i >> 2;
  const int tid = threadIdx.x;
  float aw[KTOP];
  int dl[KTOP];
#pragma unroll
  for (int j = 0; j < KTOP; ++j) {
    aw[j] = attn[bh * KTOP + j];
    dl[j] = delays[bh * KTOP + j];
  }
  const int e = chunk * 1024 + tid * 4;
  const int t = e >> 6;
  const int d = e & 63;
  const float* vb = v + (size_t)bh * LEN * DH;
  float4 acc = make_float4(0.f, 0.f, 0.f, 0.f);
#pragma unroll
  for (int j = 0; j < KTOP; ++j) {
    int src = t - dl[j];
    if (src < 0) src += LEN;
    const float4 vv = *reinterpret_cast<const float4*>(vb + (size_t)src * DH + d);
    acc.x += aw[j] * vv.x;
    acc.y += aw[j] * vv.y;
    acc.z += aw[j] * vv.z;
    acc.w += aw[j] * vv.w;
  }
  *reinterpret_cast<float4*>(out + (size_t)bh * LEN * DH + e) = acc;
}

extern "C" void kernel_launch(void* const* d_in, const int* in_sizes, int n_in,
                              void* d_out, int out_size, void* d_ws, size_t ws_size,
                              hipStream_t stream) {
  const float* q = (const float*)d_in[0];
  const float* k = (const float*)d_in[1];
  const float* v = (const float*)d_in[2];
  float* out = (float*)d_out;

  // ws layout: part (16.8 MB) | spec (1 MB) | attn | delays
  float2* part = (float2*)d_ws;
  float2* spec = part + PART_F2;
  float* attn = (float*)(spec + SPEC_F2);
  int* delays = (int*)(attn + NBH * KTOP);

  ac_fft_fwd<<<dim3(NBH * NGRP), dim3(256), 0, stream>>>(q, k, part);
  ac_reduce<<<dim3(NBH * NGRP), dim3(256), 0, stream>>>(part, spec);
  ac_fft_inv<<<dim3(NBH), dim3(256), 0, stream>>>(spec, attn, delays);
  ac_gather<<<dim3(NBH * 256), dim3(256), 0, stream>>>(v, attn, delays, out);
}